// Round 4
// baseline (1299.477 us; speedup 1.0000x reference)
//
#include <hip/hip_runtime.h>
#include <hip/hip_bf16.h>
#include <stdint.h>

// ---------------------------------------------------------------------------
// AngularAwareTemporalAttention (MI355X / gfx950)  -- round 4: async attn
// qkv GEMM (split-bf16 3-term MFMA, depth-2 prefetch; epilogue writes
// PRE-SPLIT hi/lo bf16 planes, XOR-swizzled for conflict-free LDS reads) ->
// MFMA attention (gld16 DMA staging, counted vmcnt, Q frags global->reg,
// bf16 3-term QK^T/PV, fp32 softmax) -> proj GEMM.
//
// Scratch q/k/v in d_out as u16 planes (100.7 MB <= 134 MB):
//   Q: [tile=bn*4+hl][2 hi/lo][128 t][64 d-swz]   (swz: slot d>>3 ^ (t&7))
//   K: +16777216 u16, same layout
//   V^T: +33554432 u16, [tile][2][2 vt][64 d][8 slot][8]  (slot t''>>3 ^ d&7)
// ---------------------------------------------------------------------------

typedef float f32x4 __attribute__((ext_vector_type(4)));
typedef __bf16 bf16x8 __attribute__((ext_vector_type(8)));
typedef unsigned short us8 __attribute__((ext_vector_type(8)));
typedef unsigned short u16;

#define MROWS 32768  // BN*T = 256*128

static __device__ __forceinline__ u16 bfbits(float f) {
  __bf16 h = (__bf16)f;
  return __builtin_bit_cast(u16, h);
}
static __device__ __forceinline__ float bff(u16 u) {
  return (float)__builtin_bit_cast(__bf16, u);
}
static __device__ __forceinline__ void gld16(const void* g, void* l) {
  __builtin_amdgcn_global_load_lds(
      (const __attribute__((address_space(1))) void*)g,
      (__attribute__((address_space(3))) void*)l, 16, 0, 0);
}
static __device__ __forceinline__ f32x4 mfma16(bf16x8 a, bf16x8 b, f32x4 c) {
  return __builtin_amdgcn_mfma_f32_16x16x32_bf16(a, b, c, 0, 0, 0);
}

// ---------------------------------------------------------------------------
// fp32 -> interleaved hi|lo bf16 rows: out[row][kt][64] = [hi 0..31 | lo 0..31]
// ---------------------------------------------------------------------------
__global__ __launch_bounds__(256) void k_split(const float* __restrict__ x,
                                               u16* __restrict__ xhl, int n4) {
  int i = blockIdx.x * 256 + threadIdx.x;
  if (i >= n4) return;
  float4 v = ((const float4*)x)[i];
  ushort4 h, l;
  h.x = bfbits(v.x); l.x = bfbits(v.x - bff(h.x));
  h.y = bfbits(v.y); l.y = bfbits(v.y - bff(h.y));
  h.z = bfbits(v.z); l.z = bfbits(v.z - bff(h.z));
  h.w = bfbits(v.w); l.w = bfbits(v.w - bff(h.w));
  int i4 = i << 2;
  int r = i4 >> 10, k = i4 & 1023;
  size_t o = ((size_t)r << 11) + (size_t)((k >> 5) << 6) + (k & 31);
  *(ushort4*)(xhl + o) = h;
  *(ushort4*)(xhl + o + 32) = l;
}

// transpose W (K x N) -> interleaved hi|lo rows [orow][K/32][64]; remap=1
// groups qkv cols so group g (heads 4g..4g+3) occupies rows [g*768,(g+1)*768)
__global__ void k_tsplit(const float* __restrict__ w, u16* __restrict__ thl,
                         int K, int N, int remap) {
  __shared__ float tile[32][33];
  int n0 = blockIdx.x * 32, k0 = blockIdx.y * 32;
  int tx = threadIdx.x, ty = threadIdx.y;
#pragma unroll
  for (int j = 0; j < 32; j += 8)
    tile[ty + j][tx] = w[(size_t)(k0 + ty + j) * N + n0 + tx];
  __syncthreads();
#pragma unroll
  for (int j = 0; j < 32; j += 8) {
    float v = tile[tx][ty + j];
    int n = n0 + ty + j;
    int orow = n;
    if (remap) {
      int s = n >> 10, hid = n & 1023;
      orow = (hid >> 8) * 768 + s * 256 + (hid & 255);
    }
    int k = k0 + tx;
    size_t o = ((size_t)orow << 11) + (size_t)((k >> 5) << 6) + (k & 31);
    u16 hb = bfbits(v);
    thl[o] = hb;
    thl[o + 32] = bfbits(v - bff(hb));
  }
}

__global__ void k_gbias(const float* __restrict__ b, float* __restrict__ gb) {
  int n = blockIdx.x * 256 + threadIdx.x;
  if (n >= 3072) return;
  int s = n >> 10, hid = n & 1023;
  gb[(hid >> 8) * 768 + s * 256 + (hid & 255)] = b[n];
}

__global__ void k_cos(const float* __restrict__ bv, float* __restrict__ cosb) {
  int b = blockIdx.x, t = threadIdx.x;
  __shared__ float nb[128][3];
  float x = bv[(b * 128 + t) * 3 + 0];
  float y = bv[(b * 128 + t) * 3 + 1];
  float z = bv[(b * 128 + t) * 3 + 2];
  float inv = 1.0f / (sqrtf(x * x + y * y + z * z) + 1e-6f);
  nb[t][0] = x * inv; nb[t][1] = y * inv; nb[t][2] = z * inv;
  __syncthreads();
  float xn = nb[t][0], yn = nb[t][1], zn = nb[t][2];
  for (int j = 0; j < 128; j++) {
    float c = xn * nb[j][0] + yn * nb[j][1] + zn * nb[j][2];
    c = fminf(1.0f, fmaxf(-1.0f, c));
    cosb[((size_t)b * 128 + t) * 128 + j] = c;
  }
}

// ---------------------------------------------------------------------------
// Barrier-minimal depth-2-prefetch split-bf16 MFMA GEMM. K=1024, BK=32.
// A: [M][32 kt][hi32|lo32] interleaved (AMODE 0) or fp32 [M][1024] (AMODE 1).
// MODE 0: scatter to pre-split swizzled u16 planes (see header).
// MODE 1: fp32 [row][1024] + bias.
// ---------------------------------------------------------------------------
template <int AMODE, int MODE>
__global__ __launch_bounds__(512, 2) void k_gemm(
    const u16* __restrict__ Ahl, const float* __restrict__ Af,
    const u16* __restrict__ Bhl, const float* __restrict__ bias,
    float* __restrict__ C) {
  __shared__ __align__(16) u16 sA[3][128 * 64];  // 48 KB (3-deep ring)
  __shared__ __align__(16) u16 sB[3][256 * 64];  // 96 KB
  int tid = threadIdx.x;
  int wave = tid >> 6, lane = tid & 63;
  int fr = lane & 15, fq = lane >> 4;
  int wm = wave >> 2, wn = wave & 3;

  // XCD-chunked, N-major block remap (768 / 1024 blocks; both % 8 == 0).
  int nT = gridDim.y;
  int h = blockIdx.y * gridDim.x + blockIdx.x;
  int nwg = gridDim.x * gridDim.y;
  int w = (h & 7) * (nwg >> 3) + (h >> 3);
  int rowBase = (w / nT) * 128, colBase = (w % nT) * 256;

  f32x4 acc[4][4];
#pragma unroll
  for (int i = 0; i < 4; i++)
#pragma unroll
    for (int j = 0; j < 4; j++) acc[i][j] = (f32x4){0.f, 0.f, 0.f, 0.f};

  // Per-lane staging source. LDS dest is linear (global_load_lds constraint);
  // the XOR swizzle lives in the SOURCE slot: ls = (lane&7) ^ (row&7).
  int lr = lane >> 3, ls = (lane & 7) ^ lr;
  const u16* aS = Ahl + (size_t)(rowBase + lr) * 2048 + ls * 8;
  const u16* bS = Bhl + (size_t)(colBase + lr) * 2048 + ls * 8;

  auto stageB = [&](int t, int buf) {
#pragma unroll
    for (int q = 0; q < 4; q++) {
      int R = (q * 8 + wave) * 8;  // rows R..R+7
      gld16(bS + (size_t)R * 2048 + t * 64, &sB[buf][R * 64]);
    }
  };
  auto stageA0 = [&](int t, int buf) {
#pragma unroll
    for (int q = 0; q < 2; q++) {
      int R = (q * 8 + wave) * 8;
      gld16(aS + (size_t)R * 2048 + t * 64, &sA[buf][R * 64]);
    }
  };
  auto stageA1 = [&](int t, int buf) {  // on-the-fly split of fp32 A (plan B)
    int row = tid >> 2, cs = tid & 3;
    const float* src = Af + (size_t)(rowBase + row) * 1024 + t * 32 + cs * 8;
    float4 v0 = *(const float4*)src;
    float4 v1 = *(const float4*)(src + 4);
    float vv[8] = {v0.x, v0.y, v0.z, v0.w, v1.x, v1.y, v1.z, v1.w};
    us8 hv, lv;
#pragma unroll
    for (int i = 0; i < 8; i++) {
      u16 hb = bfbits(vv[i]);
      hv[i] = hb;
      lv[i] = bfbits(vv[i] - bff(hb));
    }
    int sw = row & 7;
    *(us8*)(&sA[buf][row * 64 + ((cs ^ sw) << 3)]) = hv;
    *(us8*)(&sA[buf][row * 64 + (((cs + 4) ^ sw) << 3)]) = lv;
  };
  auto stage = [&](int t, int buf) {
    stageB(t, buf);
    if constexpr (AMODE == 0) stageA0(t, buf);
    else stageA1(t, buf);
  };

  // One K-tile, ONE barrier, ONE counted vmcnt (see round-3 comments).
  auto tile = [&](int t, int cur, int nbuf, int vmode) {
    const u16* lA = &sA[cur][0];
    const u16* lB = &sB[cur][0];
    bf16x8 fbh[4], fbl[4];
#pragma unroll
    for (int ni = 0; ni < 4; ni++) {
      int c = wn * 64 + ni * 16 + fr;
      int sw = c & 7;
      fbh[ni] = *(const bf16x8*)(&lB[c * 64 + ((fq ^ sw) << 3)]);
      fbl[ni] = *(const bf16x8*)(&lB[c * 64 + (((fq + 4) ^ sw) << 3)]);
    }
    if (t + 2 < 32) stage(t + 2, nbuf);
#pragma unroll
    for (int mi = 0; mi < 4; mi++) {
      bf16x8 fah, fal;
      int r = wm * 64 + mi * 16 + fr;
      int sw = r & 7;
      fah = *(const bf16x8*)(&lA[r * 64 + ((fq ^ sw) << 3)]);
      fal = *(const bf16x8*)(&lA[r * 64 + (((fq + 4) ^ sw) << 3)]);
#pragma unroll
      for (int ni = 0; ni < 4; ni++) {
        acc[mi][ni] = mfma16(fah, fbh[ni], acc[mi][ni]);
        acc[mi][ni] = mfma16(fah, fbl[ni], acc[mi][ni]);
        acc[mi][ni] = mfma16(fal, fbh[ni], acc[mi][ni]);
      }
    }
    if constexpr (AMODE == 1) {
      if (vmode >= 0)
        asm volatile("s_waitcnt vmcnt(0) lgkmcnt(0)" ::: "memory");
    } else {
      if (vmode == 6)
        asm volatile("s_waitcnt vmcnt(6)" ::: "memory");
      else if (vmode == 0)
        asm volatile("s_waitcnt vmcnt(0)" ::: "memory");
    }
    __builtin_amdgcn_s_barrier();
  };

  // prologue: stage tiles 0 and 1; wait only for tile 0's loads.
  stage(0, 0);
  stage(1, 1);
  if constexpr (AMODE == 0) {
    asm volatile("s_waitcnt vmcnt(6)" ::: "memory");
  } else {
    asm volatile("s_waitcnt vmcnt(0) lgkmcnt(0)" ::: "memory");
  }
  __builtin_amdgcn_s_barrier();

#pragma unroll 1
  for (int tb = 0; tb < 30; tb += 3) {
    tile(tb, 0, 2, 6);
    tile(tb + 1, 1, 0, 6);
    tile(tb + 2, 2, 1, 6);
  }
  tile(30, 0, 2, 0);
  tile(31, 1, 0, -1);

  // epilogue
  u16* C16 = (u16*)C;
#pragma unroll
  for (int mi = 0; mi < 4; mi++)
#pragma unroll
    for (int ni = 0; ni < 4; ni++)
#pragma unroll
      for (int rr = 0; rr < 4; rr++) {
        int row = rowBase + wm * 64 + mi * 16 + fq * 4 + rr;
        int col = colBase + wn * 64 + ni * 16 + fr;
        float v = acc[mi][ni][rr] + bias[col];
        if constexpr (MODE == 0) {
          int s = col >> 8, hl2 = (col >> 6) & 3, d = col & 63;
          int bn = row >> 7, t = row & 127;
          size_t tb_ = (size_t)(bn * 4 + hl2) * 16384;
          u16 hb = bfbits(v);
          u16 lb = bfbits(v - bff(hb));
          size_t o;
          if (s == 2) {
            // V^T plane: [2 vt][64 d][8 slot][8], slot = (t''>>3) ^ (d&7)
            o = (size_t)33554432 + tb_ + (size_t)((t >> 6) << 12) + d * 64 +
                ((((t >> 3) & 7) ^ (d & 7)) << 3) + (t & 7);
          } else {
            // Q/K plane: [128 t][8 slot][8], slot = (d>>3) ^ (t&7)
            o = (size_t)s * 16777216 + tb_ + t * 64 +
                (((d >> 3) ^ (t & 7)) << 3) + (d & 7);
          }
          C16[o] = hb;
          C16[o + 8192] = lb;  // lo plane
        } else {
          C[(size_t)row * 1024 + col] = v;
        }
      }
}

// ---------------------------------------------------------------------------
// MFMA attention, one block per (bn, head-in-group, 64-row Q half): 2048 blks.
// Inputs pre-split hi/lo bf16 swizzled planes -> K/V staged via gld16 DMA
// (counted vmcnt, raw barriers), Q frags global->reg. 3-term bf16 QK^T/PV,
// fp32 softmax. LDS 66.5 KB -> 2 blocks/CU. Output: interleaved hi|lo rows.
// ---------------------------------------------------------------------------
__global__ __launch_bounds__(256) void k_attn(
    const u16* __restrict__ Qp, const u16* __restrict__ Kp,
    const u16* __restrict__ Vp, const float* __restrict__ cosb,
    const float* __restrict__ absSp, u16* __restrict__ Ohl, int g) {
  __shared__ __align__(16) u16 sKV[2][2][4096];  // [buf][hi/lo][64x64 swz]
  __shared__ __align__(16) float sS[64 * 132];
  u16* sP = (u16*)sS;  // P hi/lo overwrites S in place

  int bx = blockIdx.x;
  int half = bx & 1, hl = (bx >> 1) & 3, bn = bx >> 3, b = bn >> 6;
  int tid = threadIdx.x, wave = tid >> 6, lane = tid & 63;
  int fr = lane & 15, fq = lane >> 4;
  size_t tbase = (size_t)(bn * 4 + hl) * 16384;
  float absS = absSp[0];

  const u16* Qt = Qp + tbase;
  const u16* Kt = Kp + tbase;
  const u16* Vt = Vp + tbase;

  // stage one 64-row half-plane pair (hi+lo, 16 KB) : 4 gld16 per wave
  auto stageK = [&](int kt, int buf) {
#pragma unroll
    for (int p2 = 0; p2 < 2; p2++)
#pragma unroll
      for (int q = 0; q < 2; q++) {
        int seg = (q * 4 + wave) * 512;
        gld16(Kt + p2 * 8192 + kt * 4096 + seg + lane * 8, &sKV[buf][p2][seg]);
      }
  };
  auto stageV = [&](int vt, int buf) {
#pragma unroll
    for (int p2 = 0; p2 < 2; p2++)
#pragma unroll
      for (int q = 0; q < 2; q++) {
        int seg = (q * 4 + wave) * 512;
        gld16(Vt + p2 * 8192 + vt * 4096 + seg + lane * 8, &sKV[buf][p2][seg]);
      }
  };

  // ---- issue K0, Q-frag loads, K1 (order pinned for counted vmcnt) ------
  stageK(0, 0);
  __builtin_amdgcn_sched_barrier(0);
  int rowl = wave * 16 + fr;
  int tq = half * 64 + rowl;
  bf16x8 qh[2], ql[2];
#pragma unroll
  for (int ki = 0; ki < 2; ki++) {
    int sl = ((ki * 4 + fq) ^ (tq & 7)) << 3;
    qh[ki] = *(const bf16x8*)(Qt + tq * 64 + sl);
    ql[ki] = *(const bf16x8*)(Qt + 8192 + tq * 64 + sl);
  }
  __builtin_amdgcn_sched_barrier(0);
  stageK(1, 1);
  __builtin_amdgcn_sched_barrier(0);
  // own outstanding: K0(4) Q(4) K1(4) -> vmcnt(4) drains K0+Q, K1 in flight
  asm volatile("s_waitcnt vmcnt(4)" ::: "memory");
  __builtin_amdgcn_s_barrier();  // all waves: K0 staged

  // ---- QK^T in two 64-col K halves --------------------------------------
#pragma unroll
  for (int kt = 0; kt < 2; kt++) {
#pragma unroll
    for (int nt = 0; nt < 4; nt++) {
      f32x4 a = (f32x4){0.f, 0.f, 0.f, 0.f};
      int cl = nt * 16 + fr;
#pragma unroll
      for (int ki = 0; ki < 2; ki++) {
        int sl = ((ki * 4 + fq) ^ (cl & 7)) << 3;
        bf16x8 kh = *(const bf16x8*)(&sKV[kt][0][cl * 64 + sl]);
        bf16x8 kl = *(const bf16x8*)(&sKV[kt][1][cl * 64 + sl]);
        a = mfma16(qh[ki], kh, a);
        a = mfma16(qh[ki], kl, a);
        a = mfma16(ql[ki], kh, a);
      }
#pragma unroll
      for (int rr = 0; rr < 4; rr++) {
        int rl = wave * 16 + fq * 4 + rr;
        int col = kt * 64 + nt * 16 + fr;
        int tg = half * 64 + rl;
        float cv = cosb[((size_t)(b * 128 + tg)) * 128 + col];
        sS[rl * 132 + col] = a[rr] * 0.125f + absS * cv;
      }
    }
    __builtin_amdgcn_s_barrier();  // all waves done reading sKV[kt]
    if (kt == 0) {
      stageV(0, 0);  // overwrite buf0 with V half 0
      __builtin_amdgcn_sched_barrier(0);
      // own outstanding: K1(<=4) V0(4); K1 older -> vmcnt(4) drains K1
      asm volatile("s_waitcnt vmcnt(4)" ::: "memory");
      __builtin_amdgcn_s_barrier();  // all waves: K1 staged
    }
  }
  stageV(1, 1);  // overwrite buf1 with V half 1 (barrier above covers WAR)
  __builtin_amdgcn_sched_barrier(0);

  // ---- softmax (wave-private rows; overlaps V staging) ------------------
  for (int r = 0; r < 16; r++) {
    int tl = wave * 16 + r;
    float s0 = sS[tl * 132 + lane], s1 = sS[tl * 132 + 64 + lane];
    float m = fmaxf(s0, s1);
#pragma unroll
    for (int off = 32; off >= 1; off >>= 1) m = fmaxf(m, __shfl_xor(m, off));
    float p0 = __expf(s0 - m), p1 = __expf(s1 - m);
    float sum = p0 + p1;
#pragma unroll
    for (int off = 32; off >= 1; off >>= 1) sum += __shfl_xor(sum, off);
    float inv = 1.0f / sum;
    p0 *= inv; p1 *= inv;
    u16 h0 = bfbits(p0), h1 = bfbits(p1);
    sP[tl * 264 + lane] = h0;
    sP[tl * 264 + 64 + lane] = h1;
    sP[tl * 264 + 128 + lane] = bfbits(p0 - bff(h0));
    sP[tl * 264 + 192 + lane] = bfbits(p1 - bff(h1));
  }

  // ---- PV in two 64-t V halves ------------------------------------------
  f32x4 accO[4];
#pragma unroll
  for (int nt = 0; nt < 4; nt++) accO[nt] = (f32x4){0.f, 0.f, 0.f, 0.f};
#pragma unroll
  for (int vt = 0; vt < 2; vt++) {
    if (vt == 0) {
      // own outstanding: V0(4) V1(4) -> vmcnt(4) drains V0
      asm volatile("s_waitcnt vmcnt(4)" ::: "memory");
    } else {
      asm volatile("s_waitcnt vmcnt(0)" ::: "memory");
    }
    __builtin_amdgcn_s_barrier();  // all waves: V half staged
    bf16x8 ph[2], pl[2];
#pragma unroll
    for (int ki = 0; ki < 2; ki++) {
      ph[ki] = *(const bf16x8*)(&sP[rowl * 264 + vt * 64 + ki * 32 + fq * 8]);
      pl[ki] = *(const bf16x8*)(&sP[rowl * 264 + 128 + vt * 64 + ki * 32 + fq * 8]);
    }
#pragma unroll
    for (int nt = 0; nt < 4; nt++) {
      int d = nt * 16 + fr;
#pragma unroll
      for (int ki = 0; ki < 2; ki++) {
        int sl = ((ki * 4 + fq) ^ (d & 7)) << 3;
        bf16x8 vh = *(const bf16x8*)(&sKV[vt][0][d * 64 + sl]);
        bf16x8 vl = *(const bf16x8*)(&sKV[vt][1][d * 64 + sl]);
        accO[nt] = mfma16(ph[ki], vh, accO[nt]);
        accO[nt] = mfma16(ph[ki], vl, accO[nt]);
        accO[nt] = mfma16(pl[ki], vh, accO[nt]);
      }
    }
  }

  // ---- epilogue: O -> global interleaved hi|lo bf16 ---------------------
  int hg = g * 4 + hl;
#pragma unroll
  for (int nt = 0; nt < 4; nt++)
#pragma unroll
    for (int rr = 0; rr < 4; rr++) {
      int tl = wave * 16 + fq * 4 + rr;
      int tg = half * 64 + tl;
      int d = nt * 16 + fr;
      float v = accO[nt][rr];
      size_t o = ((size_t)(bn * 128 + tg) << 11) +
                 (size_t)(hg * 2 + (d >> 5)) * 64 + (d & 31);
      u16 hh = bfbits(v);
      Ohl[o] = hh;
      Ohl[o + 32] = bfbits(v - bff(hh));
    }
}

// ---------------------------------------------------------------------------
extern "C" void kernel_launch(void* const* d_in, const int* in_sizes, int n_in,
                              void* d_out, int out_size, void* d_ws,
                              size_t ws_size, hipStream_t stream) {
  const float* x = (const float*)d_in[0];
  const float* bv = (const float*)d_in[1];
  const float* qkvw = (const float*)d_in[2];
  const float* qkvb = (const float*)d_in[3];
  const float* projw = (const float*)d_in[4];
  const float* projb = (const float*)d_in[5];
  const float* absS = (const float*)d_in[6];
  float* out = (float*)d_out;

  char* ws = (char*)d_ws;
  size_t off = 0;
  auto alloc = [&](size_t b) {
    char* p = ws + off;
    off += (b + 255) & ~(size_t)255;
    return p;
  };
  u16* wqhl = (u16*)alloc((size_t)3072 * 2048 * 2);
  u16* wphl = (u16*)alloc((size_t)1024 * 2048 * 2);
  float* gbias = (float*)alloc(3072 * 4);
  float* cosb = (float*)alloc((size_t)4 * 128 * 128 * 4);
  u16* Ohl = (u16*)alloc((size_t)MROWS * 2048 * 2);
  u16* xhl = (u16*)alloc((size_t)MROWS * 2048 * 2);  // last: plan B drops this
  bool planA = (off <= ws_size);

  u16* O16 = (u16*)d_out;  // q planes +0, k +16777216, v^T +33554432 (u16)

  k_tsplit<<<dim3(96, 32), dim3(32, 8), 0, stream>>>(qkvw, wqhl, 1024, 3072, 1);
  k_tsplit<<<dim3(32, 32), dim3(32, 8), 0, stream>>>(projw, wphl, 1024, 1024, 0);
  k_gbias<<<dim3(12), dim3(256), 0, stream>>>(qkvb, gbias);
  k_cos<<<dim3(4), dim3(128), 0, stream>>>(bv, cosb);
  if (planA)
    k_split<<<dim3(32768), dim3(256), 0, stream>>>(x, xhl, 8388608);

  for (int g = 0; g < 4; g++) {
    const u16* bw = wqhl + (size_t)g * 768 * 2048;
    if (planA)
      k_gemm<0, 0><<<dim3(256, 3), dim3(512), 0, stream>>>(
          xhl, nullptr, bw, gbias + g * 768, (float*)O16);
    else
      k_gemm<1, 0><<<dim3(256, 3), dim3(512), 0, stream>>>(
          nullptr, x, bw, gbias + g * 768, (float*)O16);
    k_attn<<<dim3(2048), dim3(256), 0, stream>>>(
        O16, O16 + 16777216, O16 + 33554432, cosb, absS, Ohl, g);
  }

  k_gemm<0, 1><<<dim3(256, 4), dim3(512), 0, stream>>>(
      Ohl, nullptr, wphl, projb, out);
}

// Round 5
// 1197.727 us; speedup vs baseline: 1.0850x; 1.0850x over previous
//
#include <hip/hip_runtime.h>
#include <hip/hip_bf16.h>
#include <stdint.h>

// ---------------------------------------------------------------------------
// AngularAwareTemporalAttention (MI355X / gfx950)  -- round 5: coalesced epi
// qkv GEMM (split-bf16 3-term MFMA, depth-2 prefetch; LDS-staged epilogue
// writes pre-split hi/lo bf16 planes as one contiguous 128KB coalesced block)
// -> MFMA attention (gld16 DMA staging, counted vmcnt, pair-XCD remap,
// LDS-staged coalesced O epilogue) -> proj GEMM.
//
// Scratch q/k/v planes in d_out as u16 (100.7 MB):
//   Q: [tile=bn*4+hl][2 hi/lo][128 t][64 d-swz]   (swz: slot d>>3 ^ (t&7))
//   K: +16777216 u16, same layout
//   V^T: +33554432 u16, [tile][2][2 vt][64 d][8 slot][8]  (slot t''>>3 ^ d&7)
// ---------------------------------------------------------------------------

typedef float f32x4 __attribute__((ext_vector_type(4)));
typedef __bf16 bf16x8 __attribute__((ext_vector_type(8)));
typedef unsigned short us8 __attribute__((ext_vector_type(8)));
typedef unsigned short u16;

#define MROWS 32768  // BN*T = 256*128

static __device__ __forceinline__ u16 bfbits(float f) {
  __bf16 h = (__bf16)f;
  return __builtin_bit_cast(u16, h);
}
static __device__ __forceinline__ float bff(u16 u) {
  return (float)__builtin_bit_cast(__bf16, u);
}
static __device__ __forceinline__ void gld16(const void* g, void* l) {
  __builtin_amdgcn_global_load_lds(
      (const __attribute__((address_space(1))) void*)g,
      (__attribute__((address_space(3))) void*)l, 16, 0, 0);
}
static __device__ __forceinline__ f32x4 mfma16(bf16x8 a, bf16x8 b, f32x4 c) {
  return __builtin_amdgcn_mfma_f32_16x16x32_bf16(a, b, c, 0, 0, 0);
}

// ---------------------------------------------------------------------------
// fp32 -> interleaved hi|lo bf16 rows: out[row][kt][64] = [hi 0..31 | lo 0..31]
// ---------------------------------------------------------------------------
__global__ __launch_bounds__(256) void k_split(const float* __restrict__ x,
                                               u16* __restrict__ xhl, int n4) {
  int i = blockIdx.x * 256 + threadIdx.x;
  if (i >= n4) return;
  float4 v = ((const float4*)x)[i];
  ushort4 h, l;
  h.x = bfbits(v.x); l.x = bfbits(v.x - bff(h.x));
  h.y = bfbits(v.y); l.y = bfbits(v.y - bff(h.y));
  h.z = bfbits(v.z); l.z = bfbits(v.z - bff(h.z));
  h.w = bfbits(v.w); l.w = bfbits(v.w - bff(h.w));
  int i4 = i << 2;
  int r = i4 >> 10, k = i4 & 1023;
  size_t o = ((size_t)r << 11) + (size_t)((k >> 5) << 6) + (k & 31);
  *(ushort4*)(xhl + o) = h;
  *(ushort4*)(xhl + o + 32) = l;
}

// transpose W (K x N) -> interleaved hi|lo rows [orow][K/32][64]; remap=1
// groups qkv cols so group g (heads 4g..4g+3) occupies rows [g*768,(g+1)*768)
__global__ void k_tsplit(const float* __restrict__ w, u16* __restrict__ thl,
                         int K, int N, int remap) {
  __shared__ float tile[32][33];
  int n0 = blockIdx.x * 32, k0 = blockIdx.y * 32;
  int tx = threadIdx.x, ty = threadIdx.y;
#pragma unroll
  for (int j = 0; j < 32; j += 8)
    tile[ty + j][tx] = w[(size_t)(k0 + ty + j) * N + n0 + tx];
  __syncthreads();
#pragma unroll
  for (int j = 0; j < 32; j += 8) {
    float v = tile[tx][ty + j];
    int n = n0 + ty + j;
    int orow = n;
    if (remap) {
      int s = n >> 10, hid = n & 1023;
      orow = (hid >> 8) * 768 + s * 256 + (hid & 255);
    }
    int k = k0 + tx;
    size_t o = ((size_t)orow << 11) + (size_t)((k >> 5) << 6) + (k & 31);
    u16 hb = bfbits(v);
    thl[o] = hb;
    thl[o + 32] = bfbits(v - bff(hb));
  }
}

__global__ void k_gbias(const float* __restrict__ b, float* __restrict__ gb) {
  int n = blockIdx.x * 256 + threadIdx.x;
  if (n >= 3072) return;
  int s = n >> 10, hid = n & 1023;
  gb[(hid >> 8) * 768 + s * 256 + (hid & 255)] = b[n];
}

__global__ void k_cos(const float* __restrict__ bv, float* __restrict__ cosb) {
  int b = blockIdx.x, t = threadIdx.x;
  __shared__ float nb[128][3];
  float x = bv[(b * 128 + t) * 3 + 0];
  float y = bv[(b * 128 + t) * 3 + 1];
  float z = bv[(b * 128 + t) * 3 + 2];
  float inv = 1.0f / (sqrtf(x * x + y * y + z * z) + 1e-6f);
  nb[t][0] = x * inv; nb[t][1] = y * inv; nb[t][2] = z * inv;
  __syncthreads();
  float xn = nb[t][0], yn = nb[t][1], zn = nb[t][2];
  for (int j = 0; j < 128; j++) {
    float c = xn * nb[j][0] + yn * nb[j][1] + zn * nb[j][2];
    c = fminf(1.0f, fmaxf(-1.0f, c));
    cosb[((size_t)b * 128 + t) * 128 + j] = c;
  }
}

// ---------------------------------------------------------------------------
// Barrier-minimal depth-2-prefetch split-bf16 MFMA GEMM. K=1024, BK=32.
// A: [M][32 kt][hi32|lo32] interleaved (AMODE 0) or fp32 [M][1024] (AMODE 1).
// MODE 0: LDS-staged epilogue -> contiguous 128KB pre-split swizzled planes.
// MODE 1: fp32 [row][1024] + bias.
// ---------------------------------------------------------------------------
template <int AMODE, int MODE>
__global__ __launch_bounds__(512, 2) void k_gemm(
    const u16* __restrict__ Ahl, const float* __restrict__ Af,
    const u16* __restrict__ Bhl, const float* __restrict__ bias,
    float* __restrict__ C) {
  __shared__ __align__(16) u16 smem[73728];  // 144 KB: A ring 3x16K, B 3x32K
  u16* sAb = smem;           // [3][128*64]
  u16* sBb = smem + 24576;   // [3][256*64]
  int tid = threadIdx.x;
  int wave = tid >> 6, lane = tid & 63;
  int fr = lane & 15, fq = lane >> 4;
  int wm = wave >> 2, wn = wave & 3;

  // XCD-chunked, N-major block remap (768 / 1024 blocks; both % 8 == 0).
  int nT = gridDim.y;
  int h = blockIdx.y * gridDim.x + blockIdx.x;
  int nwg = gridDim.x * gridDim.y;
  int w = (h & 7) * (nwg >> 3) + (h >> 3);
  int rowBase = (w / nT) * 128, colBase = (w % nT) * 256;

  f32x4 acc[4][4];
#pragma unroll
  for (int i = 0; i < 4; i++)
#pragma unroll
    for (int j = 0; j < 4; j++) acc[i][j] = (f32x4){0.f, 0.f, 0.f, 0.f};

  // Per-lane staging source. LDS dest is linear (global_load_lds constraint);
  // the XOR swizzle lives in the SOURCE slot: ls = (lane&7) ^ (row&7).
  int lr = lane >> 3, ls = (lane & 7) ^ lr;
  const u16* aS = Ahl + (size_t)(rowBase + lr) * 2048 + ls * 8;
  const u16* bS = Bhl + (size_t)(colBase + lr) * 2048 + ls * 8;

  auto stageB = [&](int t, int buf) {
#pragma unroll
    for (int q = 0; q < 4; q++) {
      int R = (q * 8 + wave) * 8;  // rows R..R+7
      gld16(bS + (size_t)R * 2048 + t * 64, &sBb[buf * 16384 + R * 64]);
    }
  };
  auto stageA0 = [&](int t, int buf) {
#pragma unroll
    for (int q = 0; q < 2; q++) {
      int R = (q * 8 + wave) * 8;
      gld16(aS + (size_t)R * 2048 + t * 64, &sAb[buf * 8192 + R * 64]);
    }
  };
  auto stageA1 = [&](int t, int buf) {  // on-the-fly split of fp32 A (plan B)
    int row = tid >> 2, cs = tid & 3;
    const float* src = Af + (size_t)(rowBase + row) * 1024 + t * 32 + cs * 8;
    float4 v0 = *(const float4*)src;
    float4 v1 = *(const float4*)(src + 4);
    float vv[8] = {v0.x, v0.y, v0.z, v0.w, v1.x, v1.y, v1.z, v1.w};
    us8 hv, lv;
#pragma unroll
    for (int i = 0; i < 8; i++) {
      u16 hb = bfbits(vv[i]);
      hv[i] = hb;
      lv[i] = bfbits(vv[i] - bff(hb));
    }
    int sw = row & 7;
    *(us8*)(&sAb[buf * 8192 + row * 64 + ((cs ^ sw) << 3)]) = hv;
    *(us8*)(&sAb[buf * 8192 + row * 64 + (((cs + 4) ^ sw) << 3)]) = lv;
  };
  auto stage = [&](int t, int buf) {
    stageB(t, buf);
    if constexpr (AMODE == 0) stageA0(t, buf);
    else stageA1(t, buf);
  };

  // One K-tile, ONE barrier, ONE counted vmcnt (see round-3 comments).
  auto tile = [&](int t, int cur, int nbuf, int vmode) {
    const u16* lA = &sAb[cur * 8192];
    const u16* lB = &sBb[cur * 16384];
    bf16x8 fbh[4], fbl[4];
#pragma unroll
    for (int ni = 0; ni < 4; ni++) {
      int c = wn * 64 + ni * 16 + fr;
      int sw = c & 7;
      fbh[ni] = *(const bf16x8*)(&lB[c * 64 + ((fq ^ sw) << 3)]);
      fbl[ni] = *(const bf16x8*)(&lB[c * 64 + (((fq + 4) ^ sw) << 3)]);
    }
    if (t + 2 < 32) stage(t + 2, nbuf);
#pragma unroll
    for (int mi = 0; mi < 4; mi++) {
      bf16x8 fah, fal;
      int r = wm * 64 + mi * 16 + fr;
      int sw = r & 7;
      fah = *(const bf16x8*)(&lA[r * 64 + ((fq ^ sw) << 3)]);
      fal = *(const bf16x8*)(&lA[r * 64 + (((fq + 4) ^ sw) << 3)]);
#pragma unroll
      for (int ni = 0; ni < 4; ni++) {
        acc[mi][ni] = mfma16(fah, fbh[ni], acc[mi][ni]);
        acc[mi][ni] = mfma16(fah, fbl[ni], acc[mi][ni]);
        acc[mi][ni] = mfma16(fal, fbh[ni], acc[mi][ni]);
      }
    }
    if constexpr (AMODE == 1) {
      if (vmode >= 0)
        asm volatile("s_waitcnt vmcnt(0) lgkmcnt(0)" ::: "memory");
    } else {
      if (vmode == 6)
        asm volatile("s_waitcnt vmcnt(6)" ::: "memory");
      else if (vmode == 0)
        asm volatile("s_waitcnt vmcnt(0)" ::: "memory");
    }
    __builtin_amdgcn_s_barrier();
  };

  // prologue: stage tiles 0 and 1; wait only for tile 0's loads.
  stage(0, 0);
  stage(1, 1);
  if constexpr (AMODE == 0) {
    asm volatile("s_waitcnt vmcnt(6)" ::: "memory");
  } else {
    asm volatile("s_waitcnt vmcnt(0) lgkmcnt(0)" ::: "memory");
  }
  __builtin_amdgcn_s_barrier();

#pragma unroll 1
  for (int tb = 0; tb < 30; tb += 3) {
    tile(tb, 0, 2, 6);
    tile(tb + 1, 1, 0, 6);
    tile(tb + 2, 2, 1, 6);
  }
  tile(30, 0, 2, 0);
  tile(31, 1, 0, -1);

  // ---- epilogue ---------------------------------------------------------
  if constexpr (MODE == 0) {
    // Stage hi/lo u16 into LDS at FINAL global layout (block output = one
    // contiguous 128KB region: 4 head-tiles x [2 hi/lo][8192]), then linear
    // coalesced copy-out (full-line dwordx4 stores, no RMW).
    int s = colBase >> 8;   // 0=q 1=k 2=v (block covers exactly one)
    int bn = rowBase >> 7;  // one bn tile per block
#pragma unroll
    for (int mi = 0; mi < 4; mi++)
#pragma unroll
      for (int ni = 0; ni < 4; ni++)
#pragma unroll
        for (int rr = 0; rr < 4; rr++) {
          int t = wm * 64 + mi * 16 + fq * 4 + rr;
          int c256 = wn * 64 + ni * 16 + fr;
          int d = c256 & 63;  // head index within block = wn
          float v = acc[mi][ni][rr] + bias[colBase + c256];
          u16 hb = bfbits(v);
          u16 lb = bfbits(v - bff(hb));
          int loff;
          if (s == 2)
            loff = wn * 16384 + ((t >> 6) << 12) + d * 64 +
                   ((((t >> 3) & 7) ^ (d & 7)) << 3) + (t & 7);
          else
            loff = wn * 16384 + t * 64 + (((d >> 3) ^ (t & 7)) << 3) + (d & 7);
          smem[loff] = hb;
          smem[loff + 8192] = lb;
        }
    __syncthreads();
    u16* C16 = (u16*)C;
    size_t gbase = (size_t)s * 16777216 + (size_t)bn * 65536;
    const uint4* srcv = (const uint4*)smem;
    uint4* dstv = (uint4*)(C16 + gbase);
#pragma unroll
    for (int i = 0; i < 16; i++) dstv[i * 512 + tid] = srcv[i * 512 + tid];
  } else {
#pragma unroll
    for (int mi = 0; mi < 4; mi++)
#pragma unroll
      for (int ni = 0; ni < 4; ni++)
#pragma unroll
        for (int rr = 0; rr < 4; rr++) {
          int row = rowBase + wm * 64 + mi * 16 + fq * 4 + rr;
          int col = colBase + wn * 64 + ni * 16 + fr;
          C[(size_t)row * 1024 + col] = acc[mi][ni][rr] + bias[col];
        }
  }
}

// ---------------------------------------------------------------------------
// MFMA attention, one block per (bn, head-in-group, 64-row Q half): 2048 blks.
// Pair-XCD remap: both 64-row halves of a head-tile land on the SAME XCD so
// the second K/V read hits that XCD's L2. K/V staged via gld16 DMA (counted
// vmcnt, raw barriers), Q frags global->reg. 3-term bf16 QK^T/PV, fp32
// softmax, setprio around MFMA. LDS-staged coalesced O epilogue.
// ---------------------------------------------------------------------------
__global__ __launch_bounds__(256) void k_attn(
    const u16* __restrict__ Qp, const u16* __restrict__ Kp,
    const u16* __restrict__ Vp, const float* __restrict__ cosb,
    const float* __restrict__ absSp, u16* __restrict__ Ohl, int g) {
  __shared__ __align__(16) u16 sKV[2][2][4096];  // [buf][hi/lo][64x64 swz]
  __shared__ __align__(16) float sS[64 * 132];
  u16* sP = (u16*)sS;  // P hi/lo overwrites S in place
  u16* sO = (u16*)sS;  // O staging reuses the same region after PV

  // pair-XCD remap: v -> (pair, half) with both halves on one XCD
  int v_ = blockIdx.x;
  int pair = (v_ & 7) * 128 + ((v_ >> 3) >> 1);
  int half = (v_ >> 3) & 1;
  int hl = pair & 3, bn = pair >> 2, b = bn >> 6;
  int tid = threadIdx.x, wave = tid >> 6, lane = tid & 63;
  int fr = lane & 15, fq = lane >> 4;
  size_t tbase = (size_t)(bn * 4 + hl) * 16384;
  float absS = absSp[0];

  const u16* Qt = Qp + tbase;
  const u16* Kt = Kp + tbase;
  const u16* Vt = Vp + tbase;

  // stage one 64-row half-plane pair (hi+lo, 16 KB) : 4 gld16 per wave
  auto stageK = [&](int kt, int buf) {
#pragma unroll
    for (int p2 = 0; p2 < 2; p2++)
#pragma unroll
      for (int q = 0; q < 2; q++) {
        int seg = (q * 4 + wave) * 512;
        gld16(Kt + p2 * 8192 + kt * 4096 + seg + lane * 8, &sKV[buf][p2][seg]);
      }
  };
  auto stageV = [&](int vt, int buf) {
#pragma unroll
    for (int p2 = 0; p2 < 2; p2++)
#pragma unroll
      for (int q = 0; q < 2; q++) {
        int seg = (q * 4 + wave) * 512;
        gld16(Vt + p2 * 8192 + vt * 4096 + seg + lane * 8, &sKV[buf][p2][seg]);
      }
  };

  // ---- issue K0, Q-frag loads, K1 (order pinned for counted vmcnt) ------
  stageK(0, 0);
  __builtin_amdgcn_sched_barrier(0);
  int rowl = wave * 16 + fr;
  int tq = half * 64 + rowl;
  bf16x8 qh[2], ql[2];
#pragma unroll
  for (int ki = 0; ki < 2; ki++) {
    int sl = ((ki * 4 + fq) ^ (tq & 7)) << 3;
    qh[ki] = *(const bf16x8*)(Qt + tq * 64 + sl);
    ql[ki] = *(const bf16x8*)(Qt + 8192 + tq * 64 + sl);
  }
  __builtin_amdgcn_sched_barrier(0);
  stageK(1, 1);
  __builtin_amdgcn_sched_barrier(0);
  // own outstanding: K0(4) Q(4) K1(4) -> vmcnt(4) drains K0+Q, K1 in flight
  asm volatile("s_waitcnt vmcnt(4)" ::: "memory");
  __builtin_amdgcn_s_barrier();  // all waves: K0 staged

  // ---- QK^T in two 64-col K halves --------------------------------------
#pragma unroll
  for (int kt = 0; kt < 2; kt++) {
    __builtin_amdgcn_s_setprio(1);
#pragma unroll
    for (int nt = 0; nt < 4; nt++) {
      f32x4 a = (f32x4){0.f, 0.f, 0.f, 0.f};
      int cl = nt * 16 + fr;
#pragma unroll
      for (int ki = 0; ki < 2; ki++) {
        int sl = ((ki * 4 + fq) ^ (cl & 7)) << 3;
        bf16x8 kh = *(const bf16x8*)(&sKV[kt][0][cl * 64 + sl]);
        bf16x8 kl = *(const bf16x8*)(&sKV[kt][1][cl * 64 + sl]);
        a = mfma16(qh[ki], kh, a);
        a = mfma16(qh[ki], kl, a);
        a = mfma16(ql[ki], kh, a);
      }
#pragma unroll
      for (int rr = 0; rr < 4; rr++) {
        int rl = wave * 16 + fq * 4 + rr;
        int col = kt * 64 + nt * 16 + fr;
        int tg = half * 64 + rl;
        float cv = cosb[((size_t)(b * 128 + tg)) * 128 + col];
        sS[rl * 132 + col] = a[rr] * 0.125f + absS * cv;
      }
    }
    __builtin_amdgcn_s_setprio(0);
    __builtin_amdgcn_s_barrier();  // all waves done reading sKV[kt]
    if (kt == 0) {
      stageV(0, 0);  // overwrite buf0 with V half 0
      __builtin_amdgcn_sched_barrier(0);
      // own outstanding: K1(<=4) V0(4); K1 older -> vmcnt(4) drains K1
      asm volatile("s_waitcnt vmcnt(4)" ::: "memory");
      __builtin_amdgcn_s_barrier();  // all waves: K1 staged
    }
  }
  stageV(1, 1);  // overwrite buf1 with V half 1 (barrier above covers WAR)
  __builtin_amdgcn_sched_barrier(0);

  // ---- softmax (wave-private rows; overlaps V staging) ------------------
  for (int r = 0; r < 16; r++) {
    int tl = wave * 16 + r;
    float s0 = sS[tl * 132 + lane], s1 = sS[tl * 132 + 64 + lane];
    float m = fmaxf(s0, s1);
#pragma unroll
    for (int off = 32; off >= 1; off >>= 1) m = fmaxf(m, __shfl_xor(m, off));
    float p0 = __expf(s0 - m), p1 = __expf(s1 - m);
    float sum = p0 + p1;
#pragma unroll
    for (int off = 32; off >= 1; off >>= 1) sum += __shfl_xor(sum, off);
    float inv = 1.0f / sum;
    p0 *= inv; p1 *= inv;
    u16 h0 = bfbits(p0), h1 = bfbits(p1);
    sP[tl * 264 + lane] = h0;
    sP[tl * 264 + 64 + lane] = h1;
    sP[tl * 264 + 128 + lane] = bfbits(p0 - bff(h0));
    sP[tl * 264 + 192 + lane] = bfbits(p1 - bff(h1));
  }

  // ---- PV in two 64-t V halves ------------------------------------------
  f32x4 accO[4];
#pragma unroll
  for (int nt = 0; nt < 4; nt++) accO[nt] = (f32x4){0.f, 0.f, 0.f, 0.f};
#pragma unroll
  for (int vt = 0; vt < 2; vt++) {
    if (vt == 0) {
      // own outstanding: V0(4) V1(4) -> vmcnt(4) drains V0
      asm volatile("s_waitcnt vmcnt(4)" ::: "memory");
    } else {
      asm volatile("s_waitcnt vmcnt(0)" ::: "memory");
    }
    __builtin_amdgcn_s_barrier();  // all waves: V half staged
    bf16x8 ph[2], pl[2];
#pragma unroll
    for (int ki = 0; ki < 2; ki++) {
      ph[ki] = *(const bf16x8*)(&sP[rowl * 264 + vt * 64 + ki * 32 + fq * 8]);
      pl[ki] = *(const bf16x8*)(&sP[rowl * 264 + 128 + vt * 64 + ki * 32 + fq * 8]);
    }
    __builtin_amdgcn_s_setprio(1);
#pragma unroll
    for (int nt = 0; nt < 4; nt++) {
      int d = nt * 16 + fr;
#pragma unroll
      for (int ki = 0; ki < 2; ki++) {
        int sl = ((ki * 4 + fq) ^ (d & 7)) << 3;
        bf16x8 vh = *(const bf16x8*)(&sKV[vt][0][d * 64 + sl]);
        bf16x8 vl = *(const bf16x8*)(&sKV[vt][1][d * 64 + sl]);
        accO[nt] = mfma16(ph[ki], vh, accO[nt]);
        accO[nt] = mfma16(ph[ki], vl, accO[nt]);
        accO[nt] = mfma16(pl[ki], vh, accO[nt]);
      }
    }
    __builtin_amdgcn_s_setprio(0);
  }

  // ---- epilogue: O -> LDS (final row layout) -> coalesced global --------
  __syncthreads();  // all waves done reading sP (sO aliases sS)
#pragma unroll
  for (int nt = 0; nt < 4; nt++)
#pragma unroll
    for (int rr = 0; rr < 4; rr++) {
      int tl = wave * 16 + fq * 4 + rr;
      int d = nt * 16 + fr;
      float v = accO[nt][rr];
      u16 hh = bfbits(v);
      u16 ll = bfbits(v - bff(hh));
      int off = tl * 136 + ((d >> 5) << 6) + (d & 31);
      sO[off] = hh;
      sO[off + 32] = ll;
    }
  __syncthreads();
  int hg = g * 4 + hl;
#pragma unroll
  for (int i = 0; i < 4; i++) {
    int c = i * 256 + tid;
    int r = c >> 4, w16 = (c & 15) << 3;
    uint4 val = *(const uint4*)(&sO[r * 136 + w16]);
    size_t go = ((size_t)(bn * 128 + half * 64 + r) << 11) + hg * 128 + w16;
    *(uint4*)(Ohl + go) = val;
  }
}

// ---------------------------------------------------------------------------
extern "C" void kernel_launch(void* const* d_in, const int* in_sizes, int n_in,
                              void* d_out, int out_size, void* d_ws,
                              size_t ws_size, hipStream_t stream) {
  const float* x = (const float*)d_in[0];
  const float* bv = (const float*)d_in[1];
  const float* qkvw = (const float*)d_in[2];
  const float* qkvb = (const float*)d_in[3];
  const float* projw = (const float*)d_in[4];
  const float* projb = (const float*)d_in[5];
  const float* absS = (const float*)d_in[6];
  float* out = (float*)d_out;

  char* ws = (char*)d_ws;
  size_t off = 0;
  auto alloc = [&](size_t b) {
    char* p = ws + off;
    off += (b + 255) & ~(size_t)255;
    return p;
  };
  u16* wqhl = (u16*)alloc((size_t)3072 * 2048 * 2);
  u16* wphl = (u16*)alloc((size_t)1024 * 2048 * 2);
  float* gbias = (float*)alloc(3072 * 4);
  float* cosb = (float*)alloc((size_t)4 * 128 * 128 * 4);
  u16* Ohl = (u16*)alloc((size_t)MROWS * 2048 * 2);
  u16* xhl = (u16*)alloc((size_t)MROWS * 2048 * 2);  // last: plan B drops this
  bool planA = (off <= ws_size);

  u16* O16 = (u16*)d_out;  // q planes +0, k +16777216, v^T +33554432 (u16)

  k_tsplit<<<dim3(96, 32), dim3(32, 8), 0, stream>>>(qkvw, wqhl, 1024, 3072, 1);
  k_tsplit<<<dim3(32, 32), dim3(32, 8), 0, stream>>>(projw, wphl, 1024, 1024, 0);
  k_gbias<<<dim3(12), dim3(256), 0, stream>>>(qkvb, gbias);
  k_cos<<<dim3(4), dim3(128), 0, stream>>>(bv, cosb);
  if (planA)
    k_split<<<dim3(32768), dim3(256), 0, stream>>>(x, xhl, 8388608);

  for (int g = 0; g < 4; g++) {
    const u16* bw = wqhl + (size_t)g * 768 * 2048;
    if (planA)
      k_gemm<0, 0><<<dim3(256, 3), dim3(512), 0, stream>>>(
          xhl, nullptr, bw, gbias + g * 768, (float*)O16);
    else
      k_gemm<1, 0><<<dim3(256, 3), dim3(512), 0, stream>>>(
          nullptr, x, bw, gbias + g * 768, (float*)O16);
    k_attn<<<dim3(2048), dim3(256), 0, stream>>>(
        O16, O16 + 16777216, O16 + 33554432, cosb, absS, Ohl, g);
  }

  k_gemm<0, 1><<<dim3(256, 4), dim3(512), 0, stream>>>(
      Ohl, nullptr, wphl, projb, out);
}